// Round 1
// baseline (699.804 us; speedup 1.0000x reference)
//
#include <hip/hip_runtime.h>

// LSTM: B=2048, T=2048, I=1, H=16, O=26.
// Layout: 32 lanes per batch element (2 batches per wave64).
//   lane = tid & 31, j = lane & 15, half = lane >> 4
//   half 0 owns gate rows { i: j,      g: 32+j }  (PyTorch gate order i,f,g,o)
//   half 1 owns gate rows { f: 16+j,   o: 48+j }
// Each lane keeps the 2x16 recurrent weight rows in VGPRs. Per step, h[16] is
// broadcast within the 32-lane group via 1 ds_write_b32 + 4 ds_read_b128
// (same-address broadcast, conflict-free, wave-internal => no barrier).
// c-update uses the pairing trick: half0 computes i*g, half1 computes f*c,
// one shfl_xor(16) + add gives c replicated in all 32 lanes.

static constexpr int T_DIM = 2048;
static constexpr int H_DIM = 16;
static constexpr int O_DIM = 26;

#define EXP2F(v) __builtin_amdgcn_exp2f(v)
#define RCPF(v)  __builtin_amdgcn_rcpf(v)

__global__ __launch_bounds__(256) void lstm_fused(
    const float* __restrict__ x,      // [B, T]
    const float* __restrict__ w_ih,   // [64]
    const float* __restrict__ w_hh,   // [64, 16]
    const float* __restrict__ b_ih,   // [64]
    const float* __restrict__ b_hh,   // [64]
    const float* __restrict__ w_out,  // [26, 16]
    const float* __restrict__ b_out,  // [26]
    float* __restrict__ out)          // [B, 26]
{
    __shared__ __align__(16) float hbuf[8][H_DIM];  // one row per 32-lane group

    const int tid  = threadIdx.x;
    const int grp  = tid >> 5;          // 0..7
    const int lane = tid & 31;
    const int j    = lane & 15;
    const int half = lane >> 4;         // 0: {i,g}, 1: {f,o}
    const int b    = (blockIdx.x << 3) + grp;

    const int row0 = (half << 4) + j;          // i (0..15) or f (16..31)
    const int row1 = 32 + (half << 4) + j;     // g (32..47) or o (48..63)

    // Recurrent weights into VGPRs (loaded once; 4 KB total, L2-resident).
    float w0[H_DIM], w1[H_DIM];
    #pragma unroll
    for (int k = 0; k < H_DIM; ++k) w0[k] = w_hh[row0 * H_DIM + k];
    #pragma unroll
    for (int k = 0; k < H_DIM; ++k) w1[k] = w_hh[row1 * H_DIM + k];

    const float wih0  = w_ih[row0];
    const float wih1  = w_ih[row1];
    const float bias0 = b_ih[row0] + b_hh[row0];
    const float bias1 = b_ih[row1] + b_hh[row1];

    const float NL2E = -1.44269504088896340736f;   // -log2(e)
    // acc1 activation: half0 -> tanh(z) = 2*sigmoid(2z)-1 ; half1 -> sigmoid(z)
    const float sA1 = half ? NL2E : 2.0f * NL2E;   // pre-scale folded with -log2e
    const float s2  = half ? 1.0f : 2.0f;          // post fma scale
    const float s3  = half ? 0.0f : -1.0f;         // post fma offset

    float c = 0.0f;   // c[j], replicated in both halves
    float h = 0.0f;   // h[j], replicated in both halves

    const float4* xp = reinterpret_cast<const float4*>(x + (size_t)b * T_DIM);
    float* hrow = hbuf[grp];

    float4 xq = xp[0];  // broadcast load: all 32 lanes of the group share addr

    for (int t4 = 0; t4 < T_DIM / 4; ++t4) {
        // software prefetch of the next 4 x-values (wraps harmlessly at end)
        float4 xnext = xp[(t4 + 1) & (T_DIM / 4 - 1)];
        const float xa[4] = {xq.x, xq.y, xq.z, xq.w};

        #pragma unroll
        for (int s = 0; s < 4; ++s) {
            // --- broadcast h within the 32-lane group via LDS ---
            hrow[j] = h;                              // 2-way dup write, identical values
            __builtin_amdgcn_wave_barrier();          // keep write before reads
            const float4 h0 = reinterpret_cast<const float4*>(hrow)[0];
            const float4 h1 = reinterpret_cast<const float4*>(hrow)[1];
            const float4 h2 = reinterpret_cast<const float4*>(hrow)[2];
            const float4 h3 = reinterpret_cast<const float4*>(hrow)[3];
            const float hr[H_DIM] = {h0.x, h0.y, h0.z, h0.w,
                                     h1.x, h1.y, h1.z, h1.w,
                                     h2.x, h2.y, h2.z, h2.w,
                                     h3.x, h3.y, h3.z, h3.w};

            // --- gate pre-activations: xg + h . w_hh[row] ---
            float acc0 = fmaf(xa[s], wih0, bias0);
            float acc1 = fmaf(xa[s], wih1, bias1);
            #pragma unroll
            for (int k = 0; k < H_DIM; ++k) {
                acc0 = fmaf(hr[k], w0[k], acc0);
                acc1 = fmaf(hr[k], w1[k], acc1);
            }

            // --- activations ---
            // sigmoid(z) = 1/(1 + exp2(z * -log2e))   (exp2 overflow -> inf -> rcp -> 0: safe)
            const float a0 = RCPF(EXP2F(acc0 * NL2E) + 1.0f);            // i or f
            const float a1 = fmaf(RCPF(EXP2F(acc1 * sA1) + 1.0f), s2, s3); // tanh(g) or o

            // --- c update: c = f*c + i*g via half-exchange ---
            const float m  = a0 * (half ? c : a1);   // half0: i*g ; half1: f*c
            const float mx = __shfl_xor(m, 16);
            c = m + mx;                               // identical in both halves

            // --- h update: h = o * tanh(c) ---
            const float th  = fmaf(RCPF(EXP2F(c * (2.0f * NL2E)) + 1.0f), 2.0f, -1.0f);
            const float a1x = __shfl_xor(a1, 16);    // unconditional: full-exec shuffle
            const float o_  = half ? a1 : a1x;       // o-gate value in every lane
            h = o_ * th;                              // identical in both halves
        }
        xq = xnext;
    }

    // --- epilogue: out[b, :] = h_last @ w_out.T + b_out ---
    hrow[j] = h;
    __builtin_amdgcn_wave_barrier();
    if (lane < O_DIM) {
        float sacc = b_out[lane];
        #pragma unroll
        for (int k = 0; k < H_DIM; ++k)
            sacc = fmaf(hrow[k], w_out[lane * H_DIM + k], sacc);
        out[(size_t)b * O_DIM + lane] = sacc;
    }
}

extern "C" void kernel_launch(void* const* d_in, const int* in_sizes, int n_in,
                              void* d_out, int out_size, void* d_ws, size_t ws_size,
                              hipStream_t stream) {
    const float* x     = (const float*)d_in[0];
    const float* w_ih  = (const float*)d_in[1];
    const float* w_hh  = (const float*)d_in[2];
    const float* b_ih  = (const float*)d_in[3];
    const float* b_hh  = (const float*)d_in[4];
    const float* w_out = (const float*)d_in[5];
    const float* b_out = (const float*)d_in[6];
    float* out = (float*)d_out;

    const int B = in_sizes[0] / T_DIM;          // 2048
    dim3 grid(B / 8), block(256);               // 256 blocks -> 1 per CU, 1 wave/SIMD
    hipLaunchKernelGGL(lstm_fused, grid, block, 0, stream,
                       x, w_ih, w_hh, b_ih, b_hh, w_out, b_out, out);
}

// Round 2
// 465.800 us; speedup vs baseline: 1.5024x; 1.5024x over previous
//
#include <hip/hip_runtime.h>

// LSTM: B=2048, T=2048, I=1, H=16, O=26.
//
// Round-2 design: zero LDS-pipe ops in the per-step critical path.
//   lane (0..63): j = lane&15 (h index), g = bit4 (batch within wave),
//                 halfb = bit5 (gate pair: 0 -> {i,g}, 1 -> {f,o})
//   Each 16-lane DPP row = one (batch, half): rows 0/1 = half0 of batch g0/g1,
//   rows 2/3 = half1. Matvec h@W^T done systolically with DPP row_ror:r
//   (VALU-speed rotations, direction resolved by runtime probes at init);
//   the i*g + f*c combine and o-broadcast cross bit5 via permlane32_swap
//   (VALU-class), output-order resolved by a one-time integer probe.
// Wave = 2 batches -> 1024 waves -> 1 wave/SIMD on 256 CUs.
// __launch_bounds__(256,1): round 1's VGPR_Count=32 showed the allocator
// squeezed the weight arrays out of registers; free it up to 512 VGPRs.

static constexpr int T_DIM = 2048;
static constexpr int H_DIM = 16;
static constexpr int O_DIM = 26;

#define EXP2F(v) __builtin_amdgcn_exp2f(v)
#define RCPF(v)  __builtin_amdgcn_rcpf(v)

// DPP row rotate within 16-lane rows; ctrl 0x120|r = row_ror:r. All ctrl args
// are literal at each use site (builtin requires immediates).
#define ROR_I(x, r) __builtin_amdgcn_update_dpp((x), (x), 0x120 + (r), 0xF, 0xF, false)
#define ROR_F(x, r) __builtin_bit_cast(float, ROR_I(__builtin_bit_cast(int, (x)), (r)))

#if __has_builtin(__builtin_amdgcn_permlane32_swap)
#define HAS_PSWAP 1
#else
#define HAS_PSWAP 0
#endif

// Partner value across the lane^32 boundary. psel_lo: precomputed per-lane
// bool saying which swap output holds our partner (probe-resolved at init).
__device__ __forceinline__ float partner32(float xf, bool psel_lo) {
#if HAS_PSWAP
    int xi = __builtin_bit_cast(int, xf);
    auto pr = __builtin_amdgcn_permlane32_swap(xi, xi, false, false);
    int lo, hi;
    __builtin_memcpy(&lo, &pr, 4);
    __builtin_memcpy(&hi, reinterpret_cast<const char*>(&pr) + 4, 4);
    return __builtin_bit_cast(float, psel_lo ? lo : hi);
#else
    (void)psel_lo;
    return __shfl_xor(xf, 32, 64);
#endif
}

__global__ __launch_bounds__(256, 1) void lstm_fused(
    const float* __restrict__ x,      // [B, T]
    const float* __restrict__ w_ih,   // [64]
    const float* __restrict__ w_hh,   // [64, 16]
    const float* __restrict__ b_ih,   // [64]
    const float* __restrict__ b_hh,   // [64]
    const float* __restrict__ w_out,  // [26, 16]
    const float* __restrict__ b_out,  // [26]
    float* __restrict__ out)          // [B, 26]
{
    const int tid   = threadIdx.x;
    const int wv    = tid >> 6;            // wave in block: 0..3
    const int lane  = tid & 63;
    const int j     = lane & 15;
    const int g     = (lane >> 4) & 1;     // batch within wave
    const bool halfb = (lane >= 32);       // gate pair select (bit5)
    const int b     = (blockIdx.x << 3) + (wv << 1) + g;

    const int row0 = (halfb ? 16 : 0) + j;        // i (0..15) or f (16..31)
    const int row1 = 32 + (halfb ? 16 : 0) + j;   // g (32..47) or o (48..63)

    // --- DPP direction probes: idx[r] = source j that row_ror:r delivers here.
    int idx[16];
    idx[0]  = j;
    idx[1]  = ROR_I(j, 1);
    idx[2]  = ROR_I(j, 2);
    idx[3]  = ROR_I(j, 3);
    idx[4]  = ROR_I(j, 4);
    idx[5]  = ROR_I(j, 5);
    idx[6]  = ROR_I(j, 6);
    idx[7]  = ROR_I(j, 7);
    idx[8]  = ROR_I(j, 8);
    idx[9]  = ROR_I(j, 9);
    idx[10] = ROR_I(j, 10);
    idx[11] = ROR_I(j, 11);
    idx[12] = ROR_I(j, 12);
    idx[13] = ROR_I(j, 13);
    idx[14] = ROR_I(j, 14);
    idx[15] = ROR_I(j, 15);

    // Pre-permuted recurrent weights so rotation r pairs with the right w.
    float wr0[16], wr1[16];
    #pragma unroll
    for (int r = 0; r < 16; ++r) {
        wr0[r] = w_hh[row0 * H_DIM + idx[r]];
        wr1[r] = w_hh[row1 * H_DIM + idx[r]];
    }

    // --- permlane32_swap output-order probe (per-lane, semantics-proof).
    bool psel_lo = false;
#if HAS_PSWAP
    {
        auto pr = __builtin_amdgcn_permlane32_swap(lane, lane, false, false);
        int lo, hi;
        __builtin_memcpy(&lo, &pr, 4);
        __builtin_memcpy(&hi, reinterpret_cast<const char*>(&pr) + 4, 4);
        psel_lo = (lo == (lane ^ 32));
    }
#endif

    const float wih0  = w_ih[row0];
    const float wih1  = w_ih[row1];
    const float bias0 = b_ih[row0] + b_hh[row0];
    const float bias1 = b_ih[row1] + b_hh[row1];

    const float NL2E  = -1.44269504088896340736f;  // -log2(e)
    const float N2L2E = 2.0f * NL2E;
    // acc1 activation: half0 -> tanh(z) = 2*sigmoid(2z)-1 ; half1 -> sigmoid(z)
    const float sA1 = halfb ? NL2E : N2L2E;
    const float s2  = halfb ? 1.0f : 2.0f;
    const float s3  = halfb ? 0.0f : -1.0f;

    float c = 0.0f, h = 0.0f;   // replicated across both halves of the batch

    const float4* xp = reinterpret_cast<const float4*>(x + (size_t)b * T_DIM);
    float4 xq = xp[0];

    for (int t4 = 0; t4 < T_DIM / 4; ++t4) {
        float4 xnext = xp[(t4 + 1) & (T_DIM / 4 - 1)];  // wraps harmlessly
        const float xa[4] = {xq.x, xq.y, xq.z, xq.w};

        #pragma unroll
        for (int s = 0; s < 4; ++s) {
            // --- all 16 alignments of h, VALU-speed, mutually independent ---
            float rr[16];
            rr[0]  = h;
            rr[1]  = ROR_F(h, 1);
            rr[2]  = ROR_F(h, 2);
            rr[3]  = ROR_F(h, 3);
            rr[4]  = ROR_F(h, 4);
            rr[5]  = ROR_F(h, 5);
            rr[6]  = ROR_F(h, 6);
            rr[7]  = ROR_F(h, 7);
            rr[8]  = ROR_F(h, 8);
            rr[9]  = ROR_F(h, 9);
            rr[10] = ROR_F(h, 10);
            rr[11] = ROR_F(h, 11);
            rr[12] = ROR_F(h, 12);
            rr[13] = ROR_F(h, 13);
            rr[14] = ROR_F(h, 14);
            rr[15] = ROR_F(h, 15);

            // --- gate pre-activations, 2 partials per row (depth 9 not 17) ---
            float p0a = fmaf(xa[s], wih0, bias0);
            float p1a = fmaf(xa[s], wih1, bias1);
            float p0b = rr[8] * wr0[8];
            float p1b = rr[8] * wr1[8];
            #pragma unroll
            for (int r = 0; r < 8; ++r) {
                p0a = fmaf(rr[r], wr0[r], p0a);
                p1a = fmaf(rr[r], wr1[r], p1a);
            }
            #pragma unroll
            for (int r = 9; r < 16; ++r) {
                p0b = fmaf(rr[r], wr0[r], p0b);
                p1b = fmaf(rr[r], wr1[r], p1b);
            }
            const float acc0 = p0a + p0b;
            const float acc1 = p1a + p1b;

            // --- activations: sigmoid(z) = 1/(1+exp2(z*-log2e)) ---
            const float a0 = RCPF(EXP2F(acc0 * NL2E) + 1.0f);              // i or f
            const float a1 = fmaf(RCPF(EXP2F(acc1 * sA1) + 1.0f), s2, s3); // tanh g or o

            // o-broadcast can start as soon as a1 is ready (off critical path)
            const float a1x = partner32(a1, psel_lo);
            const float o_  = halfb ? a1 : a1x;

            // --- c = f*c + i*tanh(g) via bit5 exchange ---
            const float m  = a0 * (halfb ? c : a1);   // half0: i*g~ ; half1: f*c
            const float mx = partner32(m, psel_lo);
            c = m + mx;                                // identical in both halves

            // --- h = o * tanh(c) ---
            const float th = fmaf(RCPF(EXP2F(c * N2L2E) + 1.0f), 2.0f, -1.0f);
            h = o_ * th;
        }
        xq = xnext;
    }

    // --- epilogue: out[b, :] = h @ w_out.T + b_out (off-loop, LDS fine) ---
    __shared__ float hb[4][2][H_DIM];
    if (!halfb) hb[wv][g][j] = h;
    __syncthreads();

    const int oi = lane & 31;          // output index
    const int bs = halfb ? 1 : 0;      // lanes 0-31 -> batch g0, 32-63 -> g1
    if (oi < O_DIM) {
        float sacc = b_out[oi];
        #pragma unroll
        for (int k = 0; k < H_DIM; ++k)
            sacc = fmaf(hb[wv][bs][k], w_out[oi * H_DIM + k], sacc);
        const int bb = (blockIdx.x << 3) + (wv << 1) + bs;
        out[(size_t)bb * O_DIM + oi] = sacc;
    }
}

extern "C" void kernel_launch(void* const* d_in, const int* in_sizes, int n_in,
                              void* d_out, int out_size, void* d_ws, size_t ws_size,
                              hipStream_t stream) {
    const float* x     = (const float*)d_in[0];
    const float* w_ih  = (const float*)d_in[1];
    const float* w_hh  = (const float*)d_in[2];
    const float* b_ih  = (const float*)d_in[3];
    const float* b_hh  = (const float*)d_in[4];
    const float* w_out = (const float*)d_in[5];
    const float* b_out = (const float*)d_in[6];
    float* out = (float*)d_out;

    const int B = in_sizes[0] / T_DIM;          // 2048
    dim3 grid(B / 8), block(256);               // 256 blocks, 1/CU, 1 wave/SIMD
    hipLaunchKernelGGL(lstm_fused, grid, block, 0, stream,
                       x, w_ih, w_hh, b_ih, b_hh, w_out, b_out, out);
}

// Round 3
// 408.203 us; speedup vs baseline: 1.7144x; 1.1411x over previous
//
#include <hip/hip_runtime.h>

// LSTM: B=2048, T=2048, I=1, H=16, O=26.
//
// Round-3: issue-bound at 1 wave/SIMD (R2: 510 cyc/step, VALUBusy 74%).
// Cuts the instruction stream:
//  - v_pk_fma_f32 (packed dual FP32 FMA): gate matvec 32 fma -> 16 pk_fma,
//    k paired with k+8, chain depth 8. Rotation pairs are independent DPPs.
//  - all activation pre-scales folded into the weights at init
//    (i/f/o rows x -log2e, g row x -2log2e), cell state kept scaled
//    (C = -2log2e * c) so every exp2 consumes its input directly.
//  - tanh epilogues collapsed to single FMAs.
// Layout (unchanged): lane = j(0..15) | bit4 = batch-in-wave | bit5 = gate
// pair (0:{i,g}, 1:{f,o}). 2 batches/wave -> 1024 waves = 1 wave/SIMD.

static constexpr int T_DIM = 2048;
static constexpr int H_DIM = 16;
static constexpr int O_DIM = 26;

typedef __attribute__((ext_vector_type(2))) float f32x2;

#define EXP2F(v) __builtin_amdgcn_exp2f(v)
#define RCPF(v)  __builtin_amdgcn_rcpf(v)

// DPP row rotate within 16-lane rows; 0x120|r = row_ror:r (r>=1).
#define ROR_I(x, r) __builtin_amdgcn_update_dpp((x), (x), 0x120 + (r), 0xF, 0xF, false)
#define ROR_F(x, r) __builtin_bit_cast(float, ROR_I(__builtin_bit_cast(int, (x)), (r)))

#if __has_builtin(__builtin_amdgcn_permlane32_swap)
#define HAS_PSWAP 1
#else
#define HAS_PSWAP 0
#endif

__device__ __forceinline__ float partner32(float xf, bool psel_lo) {
#if HAS_PSWAP
    int xi = __builtin_bit_cast(int, xf);
    auto pr = __builtin_amdgcn_permlane32_swap(xi, xi, false, false);
    int lo, hi;
    __builtin_memcpy(&lo, &pr, 4);
    __builtin_memcpy(&hi, reinterpret_cast<const char*>(&pr) + 4, 4);
    return __builtin_bit_cast(float, psel_lo ? lo : hi);
#else
    (void)psel_lo;
    return __shfl_xor(xf, 32, 64);
#endif
}

// Packed dual FP32 FMA (VOP3P, full rate on CDNA2+): d = a*b + c per half.
__device__ __forceinline__ f32x2 pk_fma(f32x2 a, f32x2 b, f32x2 c) {
    f32x2 d;
    asm("v_pk_fma_f32 %0, %1, %2, %3" : "=v"(d) : "v"(a), "v"(b), "v"(c));
    return d;
}

__global__ __launch_bounds__(256, 1) void lstm_fused(
    const float* __restrict__ x,      // [B, T]
    const float* __restrict__ w_ih,   // [64]
    const float* __restrict__ w_hh,   // [64, 16]
    const float* __restrict__ b_ih,   // [64]
    const float* __restrict__ b_hh,   // [64]
    const float* __restrict__ w_out,  // [26, 16]
    const float* __restrict__ b_out,  // [26]
    float* __restrict__ out)          // [B, 26]
{
    const int tid   = threadIdx.x;
    const int wv    = tid >> 6;            // wave in block: 0..3
    const int lane  = tid & 63;
    const int j     = lane & 15;
    const int g     = (lane >> 4) & 1;     // batch within wave
    const bool halfb = (lane >= 32);       // gate pair (0:{i,g}, 1:{f,o})
    const int b     = (blockIdx.x << 3) + (wv << 1) + g;

    const int row0 = (halfb ? 16 : 0) + j;        // i or f
    const int row1 = 32 + (halfb ? 16 : 0) + j;   // g or o

    // --- DPP direction probes (init-only): idx[r] = source j delivered here.
    int idx[16];
    idx[0]  = j;
    idx[1]  = ROR_I(j, 1);   idx[2]  = ROR_I(j, 2);
    idx[3]  = ROR_I(j, 3);   idx[4]  = ROR_I(j, 4);
    idx[5]  = ROR_I(j, 5);   idx[6]  = ROR_I(j, 6);
    idx[7]  = ROR_I(j, 7);   idx[8]  = ROR_I(j, 8);
    idx[9]  = ROR_I(j, 9);   idx[10] = ROR_I(j, 10);
    idx[11] = ROR_I(j, 11);  idx[12] = ROR_I(j, 12);
    idx[13] = ROR_I(j, 13);  idx[14] = ROR_I(j, 14);
    idx[15] = ROR_I(j, 15);

    // --- permlane32_swap output-order probe (per-lane, semantics-proof).
    bool psel_lo = false;
#if HAS_PSWAP
    {
        auto pr = __builtin_amdgcn_permlane32_swap(lane, lane, false, false);
        int lo, hi;
        __builtin_memcpy(&lo, &pr, 4);
        __builtin_memcpy(&hi, reinterpret_cast<const char*>(&pr) + 4, 4);
        psel_lo = (lo == (lane ^ 32));
    }
#endif

    // --- activation scale constants, folded into weights/biases ---
    const float L2E = 1.44269504088896340736f;
    const float SC  = -2.0f * L2E;               // g-row / cell scale
    const float sc0 = -L2E;                      // i,f,o rows
    const float sc1 = halfb ? sc0 : SC;          // row1: o (half1) / g (half0)

    // Pre-permuted, pre-scaled recurrent weights as (k, k+8) pk pairs.
    f32x2 wp0[8], wp1[8];
    #pragma unroll
    for (int r = 0; r < 8; ++r) {
        wp0[r] = (f32x2){w_hh[row0 * H_DIM + idx[r]] * sc0,
                         w_hh[row0 * H_DIM + idx[r + 8]] * sc0};
        wp1[r] = (f32x2){w_hh[row1 * H_DIM + idx[r]] * sc1,
                         w_hh[row1 * H_DIM + idx[r + 8]] * sc1};
    }
    const float wih0  = w_ih[row0] * sc0;
    const float wih1  = w_ih[row1] * sc1;
    const float bias0 = (b_ih[row0] + b_hh[row0]) * sc0;
    const float bias1 = (b_ih[row1] + b_hh[row1]) * sc1;

    // a1 post-fma constants: half0 -> SC*tanh(g) = 2SC*sig - SC ; half1 -> sig.
    const float k2 = halfb ? 1.0f : 2.0f * SC;
    const float k3 = halfb ? 0.0f : -SC;

    float C = 0.0f;   // scaled cell state: C = SC * c
    float h = 0.0f;

    const float4* xp = reinterpret_cast<const float4*>(x + (size_t)b * T_DIM);
    float4 xq = xp[0];

    for (int t4 = 0; t4 < T_DIM / 4; ++t4) {
        float4 xnext = xp[(t4 + 1) & (T_DIM / 4 - 1)];  // wraps harmlessly
        const float xa[4] = {xq.x, xq.y, xq.z, xq.w};

        #pragma unroll
        for (int s = 0; s < 4; ++s) {
            // --- 16 alignments of h as 8 pk pairs (15 independent DPPs) ---
            f32x2 rp[8];
            rp[0][0] = h;            rp[0][1] = ROR_F(h, 8);
            rp[1][0] = ROR_F(h, 1);  rp[1][1] = ROR_F(h, 9);
            rp[2][0] = ROR_F(h, 2);  rp[2][1] = ROR_F(h, 10);
            rp[3][0] = ROR_F(h, 3);  rp[3][1] = ROR_F(h, 11);
            rp[4][0] = ROR_F(h, 4);  rp[4][1] = ROR_F(h, 12);
            rp[5][0] = ROR_F(h, 5);  rp[5][1] = ROR_F(h, 13);
            rp[6][0] = ROR_F(h, 6);  rp[6][1] = ROR_F(h, 14);
            rp[7][0] = ROR_F(h, 7);  rp[7][1] = ROR_F(h, 15);

            // --- gate matvec: 8 pk_fma per row, x+bias rides in init C ---
            f32x2 p0 = pk_fma(rp[0], wp0[0], (f32x2){fmaf(xa[s], wih0, bias0), 0.0f});
            f32x2 p1 = pk_fma(rp[0], wp1[0], (f32x2){fmaf(xa[s], wih1, bias1), 0.0f});
            #pragma unroll
            for (int r = 1; r < 8; ++r) {
                p0 = pk_fma(rp[r], wp0[r], p0);
                p1 = pk_fma(rp[r], wp1[r], p1);
            }
            const float acc0 = p0[0] + p0[1];   // already scaled: -log2e * z
            const float acc1 = p1[0] + p1[1];

            // --- activations (exp2 consumes pre-scaled inputs directly) ---
            const float a0 = RCPF(EXP2F(acc0) + 1.0f);   // sigma(i) or sigma(f)
            const float s1 = RCPF(EXP2F(acc1) + 1.0f);   // sigma(2g) or sigma(o)
            const float a1 = fmaf(s1, k2, k3);           // SC*tanh(g) or sigma(o)

            // o-broadcast: off the critical path
            const float a1x = partner32(a1, psel_lo);
            const float o_  = halfb ? a1 : a1x;
            const float o2  = o_ + o_;

            // --- C' = sigma(f)*C + sigma(i)*(SC*tanh g) via bit5 exchange ---
            const float m  = a0 * (halfb ? C : a1);
            const float mx = partner32(m, psel_lo);
            C = m + mx;                                  // = SC * c'

            // --- h = o * tanh(c') = fma(sig_c, 2o, -o) ---
            const float sig_c = RCPF(EXP2F(C) + 1.0f);   // sigma(2c')
            h = fmaf(sig_c, o2, -o_);
        }
        xq = xnext;
    }

    // --- epilogue: out[b, :] = h @ w_out.T + b_out ---
    __shared__ float hb[4][2][H_DIM];
    if (!halfb) hb[wv][g][j] = h;
    __syncthreads();

    const int oi = lane & 31;
    const int bs = halfb ? 1 : 0;
    if (oi < O_DIM) {
        float sacc = b_out[oi];
        #pragma unroll
        for (int k = 0; k < H_DIM; ++k)
            sacc = fmaf(hb[wv][bs][k], w_out[oi * H_DIM + k], sacc);
        const int bb = (blockIdx.x << 3) + (wv << 1) + bs;
        out[(size_t)bb * O_DIM + oi] = sacc;
    }
}

extern "C" void kernel_launch(void* const* d_in, const int* in_sizes, int n_in,
                              void* d_out, int out_size, void* d_ws, size_t ws_size,
                              hipStream_t stream) {
    const float* x     = (const float*)d_in[0];
    const float* w_ih  = (const float*)d_in[1];
    const float* w_hh  = (const float*)d_in[2];
    const float* b_ih  = (const float*)d_in[3];
    const float* b_hh  = (const float*)d_in[4];
    const float* w_out = (const float*)d_in[5];
    const float* b_out = (const float*)d_in[6];
    float* out = (float*)d_out;

    const int B = in_sizes[0] / T_DIM;          // 2048
    dim3 grid(B / 8), block(256);               // 256 blocks, 1/CU, 1 wave/SIMD
    hipLaunchKernelGGL(lstm_fused, grid, block, 0, stream,
                       x, w_ih, w_hh, b_ih, b_hh, w_out, b_out, out);
}